// Round 3
// baseline (227.926 us; speedup 1.0000x reference)
//
#include <hip/hip_runtime.h>
#include <hip/hip_bf16.h>

#define N_NODES 20000
#define N_EDGES 32768
#define DIM 128
#define N_REL 474
#define N_BASIS 64
#define TILE_E 64
#define WSTRIDE 264                         // LDS row stride (shorts) for wmix staging
#define WMIX_BLKS 128                       // 64 col-blocks x 2 layers
#define TR_BLKS 2                           // root1/root2 transpose-pack blocks
#define GATHER_BASE (WMIX_BLKS + TR_BLKS)
#define FIN_BLKS ((N_NODES + 63) / 64)      // 313
#define LELIST 1024                         // per-relation edge-list capacity (max n_r ~110)

typedef __bf16 bf16x8 __attribute__((ext_vector_type(8)));
typedef float f32x4 __attribute__((ext_vector_type(4)));

// ---------- helpers ----------
__device__ __forceinline__ unsigned short f2b(float f) {   // RNE fp32 -> bf16 bits
    unsigned u = __float_as_uint(f);
    unsigned r = (u + 0x7FFFu + ((u >> 16) & 1u)) >> 16;
    return (unsigned short)r;
}
__device__ __forceinline__ float b2f(unsigned short s) {
    return __uint_as_float(((unsigned)s) << 16);
}
__device__ __forceinline__ __bf16 u2b(unsigned short u) {
    union { unsigned short u; __bf16 b; } c; c.u = u; return c.b;
}
// one-lane 8-dim contribution for bf16 packed rows
__device__ __forceinline__ float dot2bf(unsigned a, unsigned b, float wx, float wy) {
    return b2f((unsigned short)(a & 0xFFFFu)) * wx * b2f((unsigned short)(b & 0xFFFFu))
         + b2f((unsigned short)(a >> 16)) * wy * b2f((unsigned short)(b >> 16));
}

// ---------- stage 0 (one dispatch): blocks [0,128) wmix both layers (basis read ONCE);
//            blocks [128,130) root transpose+pack; blocks [130,1154) gather + zero ----------
__global__ __launch_bounds__(256) void prep_kernel(const float4* __restrict__ emb,
                                                   const int* __restrict__ entity,
                                                   ushort4* __restrict__ xb4,
                                                   float4* __restrict__ zreg, int zcount4,
                                                   const float* __restrict__ att1,
                                                   const float* __restrict__ basis1,
                                                   unsigned short* __restrict__ W1,
                                                   const float* __restrict__ att2,
                                                   const float* __restrict__ basis2,
                                                   unsigned short* __restrict__ W2,
                                                   const float* __restrict__ root1,
                                                   unsigned short* __restrict__ rootT1,
                                                   const float* __restrict__ root2,
                                                   unsigned short* __restrict__ rootT2) {
    __shared__ __align__(16) unsigned short bt[64 * WSTRIDE];   // 33792 B
    int t = threadIdx.x;
    if (blockIdx.x < WMIX_BLKS) {
        int wi = blockIdx.x;                        // 0..127
        const float* att   = (wi >= 64) ? att2 : att1;
        const float* basis = (wi >= 64) ? basis2 : basis1;
        unsigned short* W  = (wi >= 64) ? W2 : W1;
        int io0 = (wi & 63) * 256;
        // stage basis tile [64 k][256 cols] bf16, XOR-swizzled on o bits 4..6 by (k>>3)&7
#pragma unroll
        for (int p = 0; p < 16; p++) {
            int c = t + 256 * p;
            int k = c >> 6, of = c & 63;
            float4 v = *(const float4*)(basis + (size_t)k * (DIM * DIM) + io0 + of * 4);
            ushort4 s;
            s.x = f2b(v.x); s.y = f2b(v.y); s.z = f2b(v.z); s.w = f2b(v.w);
            int ofx = of ^ (((k >> 3) & 7) << 2);
            *(ushort4*)&bt[k * WSTRIDE + ofx * 4] = s;
        }
        __syncthreads();

        int w = t >> 6, l = t & 63, n = l & 15, q = l >> 4;
        // hoist b-frags: rg-invariant
        bf16x8 bfr[2][4];
#pragma unroll
        for (int kb = 0; kb < 2; kb++) {
            int kbase = kb * 32 + q * 8;
            int sx = ((kb * 4 + q) & 7) << 4;
#pragma unroll
            for (int c = 0; c < 4; c++) {
                int ob = (w * 64 + c * 16 + n) ^ sx;
#pragma unroll
                for (int j = 0; j < 8; j++) bfr[kb][c][j] = u2b(bt[(kbase + j) * WSTRIDE + ob]);
            }
        }
#pragma unroll 1
        for (int rg = 0; rg < 8; rg++) {
            int r0 = rg * 64;
            f32x4 acc[4][4] = {};                   // [rt][c]
#pragma unroll
            for (int kb = 0; kb < 2; kb++) {
                int kbase = kb * 32 + q * 8;
                bf16x8 a[4];
#pragma unroll
                for (int rt = 0; rt < 4; rt++) {
                    int rm = min(r0 + rt * 16 + n, N_REL - 1);
                    const float4* ap = (const float4*)(att + (size_t)rm * N_BASIS + kbase);
                    float4 u0 = ap[0], u1 = ap[1];
                    a[rt][0] = (__bf16)u0.x; a[rt][1] = (__bf16)u0.y;
                    a[rt][2] = (__bf16)u0.z; a[rt][3] = (__bf16)u0.w;
                    a[rt][4] = (__bf16)u1.x; a[rt][5] = (__bf16)u1.y;
                    a[rt][6] = (__bf16)u1.z; a[rt][7] = (__bf16)u1.w;
                }
#pragma unroll
                for (int c = 0; c < 4; c++) {
#pragma unroll
                    for (int rt = 0; rt < 4; rt++)
                        acc[rt][c] = __builtin_amdgcn_mfma_f32_16x16x32_bf16(a[rt], bfr[kb][c], acc[rt][c], 0, 0, 0);
                }
            }
#pragma unroll
            for (int rt = 0; rt < 4; rt++) {
#pragma unroll
                for (int c = 0; c < 4; c++) {
                    int col = io0 + w * 64 + c * 16 + n;
#pragma unroll
                    for (int g = 0; g < 4; g++) {
                        int r = r0 + rt * 16 + q * 4 + g;
                        if (r < N_REL) W[(size_t)r * (DIM * DIM) + col] = f2b(acc[rt][c][g]);
                    }
                }
            }
        }
    } else if (blockIdx.x < GATHER_BASE) {
        // root transpose+pack: rootT[o][k] = bf16(root[k][o])
        int wi2 = blockIdx.x - WMIX_BLKS;
        const float* rm = wi2 ? root2 : root1;
        unsigned short* rt_ = wi2 ? rootT2 : rootT1;
        unsigned short* sb16 = bt;                  // reuse as [k:128][stride 132]
#pragma unroll
        for (int p = 0; p < 16; p++) {
            int idx = t + 256 * p;
            int k = idx >> 5, o4 = idx & 31;
            float4 v = ((const float4*)rm)[idx];
            ushort4 s;
            s.x = f2b(v.x); s.y = f2b(v.y); s.z = f2b(v.z); s.w = f2b(v.w);
            *(ushort4*)&sb16[k * 132 + o4 * 4] = s;
        }
        __syncthreads();
        int o = t >> 1, kh = (t & 1) * 64;
#pragma unroll
        for (int i = 0; i < 16; i++) {
            int k0 = kh + i * 4;
            ushort4 s;
            s.x = sb16[(k0 + 0) * 132 + o];
            s.y = sb16[(k0 + 1) * 132 + o];
            s.z = sb16[(k0 + 2) * 132 + o];
            s.w = sb16[(k0 + 3) * 132 + o];
            *(ushort4*)&rt_[o * DIM + k0] = s;
        }
    } else {
        int pb = blockIdx.x - GATHER_BASE;
        int gtid = pb * 256 + t;
        int gsz = 1024 * 256;
        int total4 = N_NODES * DIM / 4;
        for (int i = gtid; i < total4; i += gsz) {
            int n = i >> 5, rem = i & 31;
            float4 v = emb[(size_t)entity[n] * 32 + rem];
            ushort4 s;
            s.x = f2b(v.x); s.y = f2b(v.y); s.z = f2b(v.z); s.w = f2b(v.w);
            xb4[i] = s;
        }
        float4 z = make_float4(0.f, 0.f, 0.f, 0.f);
        for (int i = gtid; i < zcount4; i += gsz) zreg[i] = z;
    }
}

// ---------- msg: one block per relation. Self-plans edge list (ballot-compact over etype),
//            computes logits inline (4 lanes/edge), MFMA messages, accumulates
//            alpha*msg into accm (denominator factored out) + alpha into den. ----------
__global__ __launch_bounds__(256) void msg_kernel(const unsigned short* __restrict__ xb,
                                                  const unsigned short* __restrict__ W,
                                                  const float* __restrict__ wlog,
                                                  const int* __restrict__ src,
                                                  const int* __restrict__ dst,
                                                  const int* __restrict__ etype,
                                                  float* __restrict__ den,
                                                  float* __restrict__ accm) {
    int r = blockIdx.x;
    const unsigned short* Wr = W + (size_t)r * (DIM * DIM);

    __shared__ __align__(16) unsigned short wt[128 * 136];   // 34816 B, swizzled
    __shared__ __align__(16) unsigned short xjf[8192];       // 16384 B, A-frag order
    __shared__ __align__(16) float wf[DIM];                  // logit weight vector
    __shared__ float scf[TILE_E];
    __shared__ int sdd[TILE_E];
    __shared__ int ssrc[TILE_E];
    __shared__ int elist[LELIST];
    __shared__ int lcnt;

    int t = threadIdx.x;
    if (t == 0) lcnt = 0;
    // stage W_r swizzled (independent of planning)
#pragma unroll
    for (int p = 0; p < 8; p++) {
        int c = t + 256 * p;
        int k = c >> 4, oct = c & 15;
        int4 v = *(const int4*)(Wr + k * DIM + oct * 8);
        int oct2 = oct ^ (((k >> 3) & 7) << 1);
        *(int4*)&wt[k * 136 + oct2 * 8] = v;
    }
    if (t < 32) ((float4*)wf)[t] = ((const float4*)(wlog + (size_t)r * DIM))[t];
    __syncthreads();   // lcnt=0 visible before planning atomics

    // ---- self-plan: compact edges with etype==r into elist ----
    int lane = t & 63;
    for (int it = 0; it < N_EDGES / 1024; it++) {   // 32 iters, int4 over L2-hot etype
        int idx = it * 256 + t;
        int4 ev = ((const int4*)etype)[idx];
#pragma unroll
        for (int j = 0; j < 4; j++) {
            int etj = (j == 0) ? ev.x : (j == 1) ? ev.y : (j == 2) ? ev.z : ev.w;
            bool m = (etj == r);
            unsigned long long bal = __ballot(m);
            int tot = __popcll(bal);
            if (tot) {
                int base = 0;
                if (lane == 0) base = atomicAdd(&lcnt, tot);
                base = __shfl(base, 0, 64);
                if (m) {
                    int pre = __popcll(bal & ((1ull << lane) - 1ull));
                    int p_ = base + pre;
                    if (p_ < LELIST) elist[p_] = idx * 4 + j;
                }
            }
        }
    }
    __syncthreads();
    int cnt = min(lcnt, LELIST);
    if (cnt == 0) return;

    int w = t >> 6, l = t & 63, n = l & 15, q = l >> 4;
    int el4 = t >> 2, l4 = t & 3;

    for (int t0 = 0; t0 < cnt; t0 += TILE_E) {
        int nE = min(TILE_E, cnt - t0);
        if (t < TILE_E) {
            if (t < nE) {
                int e = elist[t0 + t];
                ssrc[t] = src[e];
                sdd[t]  = dst[e];
            } else { ssrc[t] = 0; sdd[t] = 0; }
        }
        __syncthreads();

        // ---- logits: 4 lanes per edge, 32 dims each ----
        {
            int s_ = ssrc[el4], d_ = sdd[el4];
            const int4* xj = (const int4*)(xb + (size_t)s_ * DIM) + l4 * 4;
            const int4* xi = (const int4*)(xb + (size_t)d_ * DIM) + l4 * 4;
            const float4* wv = (const float4*)&wf[l4 * 32];
            float v = 0.f;
#pragma unroll
            for (int u = 0; u < 4; u++) {
                int4 a = xj[u]; int4 b = xi[u];
                float4 w0 = wv[u * 2], w1 = wv[u * 2 + 1];
                v += dot2bf((unsigned)a.x, (unsigned)b.x, w0.x, w0.y)
                   + dot2bf((unsigned)a.y, (unsigned)b.y, w0.z, w0.w)
                   + dot2bf((unsigned)a.z, (unsigned)b.z, w1.x, w1.y)
                   + dot2bf((unsigned)a.w, (unsigned)b.w, w1.z, w1.w);
            }
            v += __shfl_xor(v, 1, 64);
            v += __shfl_xor(v, 2, 64);
            if (l4 == 0) {
                if (el4 < nE) {
                    float a = expf(v);
                    scf[el4] = a;
                    atomicAdd(&den[d_], a);
                } else scf[el4] = 0.f;
            }
        }

        // ---- stage A-frags (x_j rows, bf16) ----
#pragma unroll
        for (int p = 0; p < 4; p++) {
            int c = t + 256 * p;
            int g = c >> 6;
            int rt = g >> 2, kb = g & 3;
            int q2 = (c >> 4) & 3, m = c & 15;
            int e = rt * 16 + m;
            int oct = kb * 4 + q2;
            int4 v = make_int4(0, 0, 0, 0);
            if (e < nE) v = *(const int4*)(xb + (size_t)ssrc[e] * DIM + oct * 8);
            *(int4*)&xjf[c * 8] = v;
        }
        __syncthreads();

        // ---- MFMA (64 x 128) @ (128 x 128) ----
        f32x4 acc[2][4] = {};
#pragma unroll
        for (int kb = 0; kb < 4; kb++) {
            bf16x8 a[4];
#pragma unroll
            for (int rt = 0; rt < 4; rt++) a[rt] = *(const bf16x8*)&xjf[((rt * 4 + kb) * 64 + l) * 8];
            int kbase = kb * 32 + q * 8;
            int sx = ((kb * 4 + q) & 7) << 4;
#pragma unroll
            for (int c = 0; c < 2; c++) {
                int ob = ((w * 2 + c) * 16 + n) ^ sx;
                bf16x8 b;
#pragma unroll
                for (int j = 0; j < 8; j++) b[j] = u2b(wt[(kbase + j) * 136 + ob]);
#pragma unroll
                for (int rt = 0; rt < 4; rt++)
                    acc[c][rt] = __builtin_amdgcn_mfma_f32_16x16x32_bf16(a[rt], b, acc[c][rt], 0, 0, 0);
            }
        }
        // ---- alpha-weighted scatter ----
#pragma unroll
        for (int c = 0; c < 2; c++) {
            int col = (w * 2 + c) * 16 + n;
#pragma unroll
            for (int rt = 0; rt < 4; rt++) {
#pragma unroll
                for (int rg = 0; rg < 4; rg++) {
                    int e = rt * 16 + q * 4 + rg;
                    if (e < nE)
                        atomicAdd(&accm[(size_t)sdd[e] * DIM + col], scf[e] * acc[c][rt][rg]);
                }
            }
        }
        __syncthreads();   // protect LDS before next tile
    }
}

// ---------- fin: rootgemm + normalize-merge.  out = x@root + bias + accm/den.
//            outb!=null -> relu + bf16 pack (layer-1 h); else fp32 write (final). ----------
__global__ __launch_bounds__(256) void fin_kernel(const unsigned short* __restrict__ xb,
                                                  const unsigned short* __restrict__ rootT,
                                                  const float* __restrict__ bias,
                                                  const float* __restrict__ accm,
                                                  const float* __restrict__ den,
                                                  float* __restrict__ outf,
                                                  unsigned short* __restrict__ outb) {
    __shared__ __align__(16) unsigned short xrf[8192];
    int t = threadIdx.x;
    int n0 = blockIdx.x * 64;
#pragma unroll
    for (int p = 0; p < 4; p++) {
        int c = t + 256 * p;
        int g = c >> 6;
        int rt = g >> 2, kb = g & 3;
        int q = (c >> 4) & 3, m = c & 15;
        int row = n0 + rt * 16 + m;
        int oct = kb * 4 + q;
        int4 v = make_int4(0, 0, 0, 0);
        if (row < N_NODES) v = *(const int4*)(xb + (size_t)row * DIM + oct * 8);
        *(int4*)&xrf[c * 8] = v;
    }
    __syncthreads();

    int w_ = t >> 6, l = t & 63, n = l & 15, q = l >> 4;
    f32x4 acc[2][4] = {};
#pragma unroll
    for (int kb = 0; kb < 4; kb++) {
        bf16x8 a[4];
#pragma unroll
        for (int rt = 0; rt < 4; rt++) a[rt] = *(const bf16x8*)&xrf[((rt * 4 + kb) * 64 + l) * 8];
        int kbase = kb * 32 + q * 8;
#pragma unroll
        for (int c = 0; c < 2; c++) {
            int col = (w_ * 2 + c) * 16 + n;
            bf16x8 b = *(const bf16x8*)(rootT + (size_t)col * DIM + kbase);
#pragma unroll
            for (int rt = 0; rt < 4; rt++)
                acc[c][rt] = __builtin_amdgcn_mfma_f32_16x16x32_bf16(a[rt], b, acc[c][rt], 0, 0, 0);
        }
    }
#pragma unroll
    for (int c = 0; c < 2; c++) {
        int col = (w_ * 2 + c) * 16 + n;
        float bo = bias[col];
#pragma unroll
        for (int rt = 0; rt < 4; rt++) {
#pragma unroll
            for (int rg = 0; rg < 4; rg++) {
                int row = n0 + rt * 16 + q * 4 + rg;
                if (row < N_NODES) {
                    float dv = den[row];
                    float mv = accm[(size_t)row * DIM + col];
                    float val = acc[c][rt][rg] + bo + (dv > 0.f ? mv / dv : 0.f);
                    if (outb) outb[(size_t)row * DIM + col] = f2b(fmaxf(val, 0.f));
                    else      outf[(size_t)row * DIM + col] = val;
                }
            }
        }
    }
}

extern "C" void kernel_launch(void* const* d_in, const int* in_sizes, int n_in,
                              void* d_out, int out_size, void* d_ws, size_t ws_size,
                              hipStream_t stream) {
    const int N = N_NODES, E = N_EDGES, R = N_REL;

    const int* entity = (const int*)d_in[0];
    const int* eidx   = (const int*)d_in[1];
    const int* src    = eidx;
    const int* dst    = eidx + E;
    const int* etype  = (const int*)d_in[2];
    const float* emb  = (const float*)d_in[3];
    const float* basis1 = (const float*)d_in[4];
    const float* att1   = (const float*)d_in[5];
    const float* w1     = (const float*)d_in[6];
    const float* root1  = (const float*)d_in[7];
    const float* bias1  = (const float*)d_in[8];
    const float* basis2 = (const float*)d_in[9];
    const float* att2   = (const float*)d_in[10];
    const float* w2     = (const float*)d_in[11];
    const float* root2  = (const float*)d_in[12];
    const float* bias2  = (const float*)d_in[13];
    float* out = (float*)d_out;

    size_t off = 0;
    auto alloc = [&](size_t bytes) -> void* {
        void* p = (char*)d_ws + off;
        off += (bytes + 255) & ~(size_t)255;
        return p;
    };
    unsigned short* W1 = (unsigned short*)alloc((size_t)R * DIM * DIM * 2);
    unsigned short* W2 = (unsigned short*)alloc((size_t)R * DIM * DIM * 2);
    unsigned short* xb = (unsigned short*)alloc((size_t)N * DIM * 2);
    unsigned short* hb = (unsigned short*)alloc((size_t)N * DIM * 2);
    // zero region: den1 | den2 | accm1 | accm2 (contiguous)
    float* zreg   = (float*)alloc(((size_t)2 * N + (size_t)2 * N * DIM) * 4);
    float* den1   = zreg;
    float* den2   = zreg + N;
    float* accm1  = zreg + 2 * N;
    float* accm2  = zreg + 2 * N + (size_t)N * DIM;
    unsigned short* rootT1 = (unsigned short*)alloc((size_t)DIM * DIM * 2);
    unsigned short* rootT2 = (unsigned short*)alloc((size_t)DIM * DIM * 2);

    int zcount4 = (2 * N + 2 * N * DIM) / 4;

    // ---- stage 0: wmix(both) + root transpose + gather + zero ----
    prep_kernel<<<GATHER_BASE + 1024, 256, 0, stream>>>(
        (const float4*)emb, entity, (ushort4*)xb, (float4*)zreg, zcount4,
        att1, basis1, W1, att2, basis2, W2, root1, rootT1, root2, rootT2);

    // ---- layer 1 ----
    msg_kernel<<<N_REL, 256, 0, stream>>>(xb, W1, w1, src, dst, etype, den1, accm1);
    fin_kernel<<<FIN_BLKS, 256, 0, stream>>>(xb, rootT1, bias1, accm1, den1, nullptr, hb);

    // ---- layer 2 (bf16 h path, identical structure) ----
    msg_kernel<<<N_REL, 256, 0, stream>>>(hb, W2, w2, src, dst, etype, den2, accm2);
    fin_kernel<<<FIN_BLKS, 256, 0, stream>>>(hb, rootT2, bias2, accm2, den2, out, nullptr);
}

// Round 5
// 215.345 us; speedup vs baseline: 1.0584x; 1.0584x over previous
//
#include <hip/hip_runtime.h>
#include <hip/hip_bf16.h>

#define N_NODES 20000
#define N_EDGES 32768
#define DIM 128
#define N_REL 474
#define N_BASIS 64
#define TILE_E 64
#define WSTRIDE 264                         // LDS row stride (shorts), 264*64*2 = 33792 B
#define LELIST 1024

// prep block layout
#define WMIX_BLKS 128                       // 64 col-blocks x 2 layers
#define ROOTT_BLK 1                         // rootT2 transpose-pack
#define RG1_BASE (WMIX_BLKS + ROOTT_BLK)    // 129
#define RG1_BLKS ((N_NODES + 63) / 64)      // 313: layer-1 rootgemm
#define GATHER_BASE (RG1_BASE + RG1_BLKS)   // 442
#define PREP_GRID 1024

#define MSG_REL_BLKS (2 * N_REL)            // 948: two blocks per relation
#define MERGE_GRID 1024

typedef __bf16 bf16x8 __attribute__((ext_vector_type(8)));
typedef float f32x4 __attribute__((ext_vector_type(4)));

// ---------- helpers ----------
__device__ __forceinline__ unsigned short f2b(float f) {   // RNE fp32 -> bf16 bits
    unsigned u = __float_as_uint(f);
    unsigned r = (u + 0x7FFFu + ((u >> 16) & 1u)) >> 16;
    return (unsigned short)r;
}
__device__ __forceinline__ float b2f(unsigned short s) {
    return __uint_as_float(((unsigned)s) << 16);
}
__device__ __forceinline__ __bf16 u2b(unsigned short u) {
    union { unsigned short u; __bf16 b; } c; c.u = u; return c.b;
}
__device__ __forceinline__ int4 pack8(float4 a0, float4 a1) {   // 8 fp32 -> bf16x8 bits
    int4 v;
    v.x = (int)((unsigned)f2b(a0.x) | ((unsigned)f2b(a0.y) << 16));
    v.y = (int)((unsigned)f2b(a0.z) | ((unsigned)f2b(a0.w) << 16));
    v.z = (int)((unsigned)f2b(a1.x) | ((unsigned)f2b(a1.y) << 16));
    v.w = (int)((unsigned)f2b(a1.z) | ((unsigned)f2b(a1.w) << 16));
    return v;
}
__device__ __forceinline__ float dot2bf(unsigned a, unsigned b, float wx, float wy) {
    return b2f((unsigned short)(a & 0xFFFFu)) * wx * b2f((unsigned short)(b & 0xFFFFu))
         + b2f((unsigned short)(a >> 16)) * wy * b2f((unsigned short)(b >> 16));
}

// ---------- prep: [0,128) wmix both layers; [128] rootT2 pack; [129,442) rootgemm1;
//            [442,1024) gather emb->bf16 + zero den/accm ----------
__global__ __launch_bounds__(256) void prep_kernel(const float4* __restrict__ emb,
                                                   const int* __restrict__ entity,
                                                   ushort4* __restrict__ xb4,
                                                   float4* __restrict__ zreg, int zcount4,
                                                   const float* __restrict__ att1,
                                                   const float* __restrict__ basis1,
                                                   unsigned short* __restrict__ W1,
                                                   const float* __restrict__ att2,
                                                   const float* __restrict__ basis2,
                                                   unsigned short* __restrict__ W2,
                                                   const float* __restrict__ root1,
                                                   float* __restrict__ racc1,
                                                   const float* __restrict__ root2,
                                                   unsigned short* __restrict__ rootT2) {
    __shared__ __align__(16) unsigned short bt[64 * WSTRIDE];   // 33792 B
    int t = threadIdx.x;
    if (blockIdx.x < WMIX_BLKS) {
        // ---- wmix: W_r[:, io0:io0+256] = att_r . basis, both layers ----
        int wi = blockIdx.x;
        const float* att   = (wi >= 64) ? att2 : att1;
        const float* basis = (wi >= 64) ? basis2 : basis1;
        unsigned short* W  = (wi >= 64) ? W2 : W1;
        int io0 = (wi & 63) * 256;
#pragma unroll
        for (int p = 0; p < 16; p++) {
            int c = t + 256 * p;
            int k = c >> 6, of = c & 63;
            float4 v = *(const float4*)(basis + (size_t)k * (DIM * DIM) + io0 + of * 4);
            ushort4 s;
            s.x = f2b(v.x); s.y = f2b(v.y); s.z = f2b(v.z); s.w = f2b(v.w);
            int ofx = of ^ (((k >> 3) & 7) << 2);
            *(ushort4*)&bt[k * WSTRIDE + ofx * 4] = s;
        }
        __syncthreads();

        int w = t >> 6, l = t & 63, n = l & 15, q = l >> 4;
        // hoist b-frags (rg-invariant); after this, bt is reusable as store-stage buffer
        bf16x8 bfr[2][4];
#pragma unroll
        for (int kb = 0; kb < 2; kb++) {
            int kbase = kb * 32 + q * 8;
            int sx = ((kb * 4 + q) & 7) << 4;
#pragma unroll
            for (int c = 0; c < 4; c++) {
                int ob = (w * 64 + c * 16 + n) ^ sx;
#pragma unroll
                for (int j = 0; j < 8; j++) bfr[kb][c][j] = u2b(bt[(kbase + j) * WSTRIDE + ob]);
            }
        }
        __syncthreads();   // all waves done reading bt

        int srow = t >> 2, sseg = t & 3;    // store mapping: 4 threads per row, 64B-int4 chunks
#pragma unroll 1
        for (int rg = 0; rg < 8; rg++) {
            int r0 = rg * 64;
            f32x4 acc[4][4] = {};
#pragma unroll
            for (int kb = 0; kb < 2; kb++) {
                int kbase = kb * 32 + q * 8;
                bf16x8 a[4];
#pragma unroll
                for (int rt = 0; rt < 4; rt++) {
                    int rm = min(r0 + rt * 16 + n, N_REL - 1);
                    const float4* ap = (const float4*)(att + (size_t)rm * N_BASIS + kbase);
                    float4 u0 = ap[0], u1 = ap[1];
                    a[rt][0] = (__bf16)u0.x; a[rt][1] = (__bf16)u0.y;
                    a[rt][2] = (__bf16)u0.z; a[rt][3] = (__bf16)u0.w;
                    a[rt][4] = (__bf16)u1.x; a[rt][5] = (__bf16)u1.y;
                    a[rt][6] = (__bf16)u1.z; a[rt][7] = (__bf16)u1.w;
                }
#pragma unroll
                for (int c = 0; c < 4; c++) {
#pragma unroll
                    for (int rt = 0; rt < 4; rt++)
                        acc[rt][c] = __builtin_amdgcn_mfma_f32_16x16x32_bf16(a[rt], bfr[kb][c], acc[rt][c], 0, 0, 0);
                }
            }
            // stage 64 r-rows x 256 cols into bt (row stride 264 shorts)
#pragma unroll
            for (int rt = 0; rt < 4; rt++) {
#pragma unroll
                for (int c = 0; c < 4; c++) {
#pragma unroll
                    for (int g = 0; g < 4; g++)
                        bt[(rt * 16 + q * 4 + g) * WSTRIDE + w * 64 + c * 16 + n] = f2b(acc[rt][c][g]);
                }
            }
            __syncthreads();
            // coalesced store: each row is a contiguous 512B run of W_r
            int rr = r0 + srow;
            if (rr < N_REL) {
                const int4* sp = (const int4*)&bt[srow * WSTRIDE];
                unsigned short* wp = W + (size_t)rr * (DIM * DIM) + io0;
#pragma unroll
                for (int ii = 0; ii < 8; ii++) {
                    int i = (ii + sseg * 2) & 7;          // seg-rotated LDS reads: ~conflict-free
                    int4 v = sp[sseg * 8 + i];
                    *(int4*)(wp + sseg * 64 + i * 8) = v;
                }
            }
            __syncthreads();
        }
    } else if (blockIdx.x < RG1_BASE) {
        // ---- rootT2 transpose+pack: rootT2[o][k] = bf16(root2[k][o]) ----
        unsigned short* sb16 = bt;                  // [k:128][stride 132]
#pragma unroll
        for (int p = 0; p < 16; p++) {
            int idx = t + 256 * p;
            int k = idx >> 5, o4 = idx & 31;
            float4 v = ((const float4*)root2)[idx];
            ushort4 s;
            s.x = f2b(v.x); s.y = f2b(v.y); s.z = f2b(v.z); s.w = f2b(v.w);
            *(ushort4*)&sb16[k * 132 + o4 * 4] = s;
        }
        __syncthreads();
        int o = t >> 1, kh = (t & 1) * 64;
#pragma unroll
        for (int i = 0; i < 16; i++) {
            int k0 = kh + i * 4;
            ushort4 s;
            s.x = sb16[(k0 + 0) * 132 + o];
            s.y = sb16[(k0 + 1) * 132 + o];
            s.z = sb16[(k0 + 2) * 132 + o];
            s.w = sb16[(k0 + 3) * 132 + o];
            *(ushort4*)&rootT2[o * DIM + k0] = s;
        }
    } else if (blockIdx.x < GATHER_BASE) {
        // ---- rootgemm1: racc1 = x @ root1 (x = bf16(emb[entity]) inline, no bias) ----
        int n0 = (blockIdx.x - RG1_BASE) * 64;
        unsigned short* xrf = bt;                   // 16 KB of bt
#pragma unroll
        for (int p = 0; p < 4; p++) {
            int c = t + 256 * p;
            int g = c >> 6;
            int rt = g >> 2, kb = g & 3;
            int q2 = (c >> 4) & 3, m = c & 15;
            int row = n0 + rt * 16 + m;
            int oct = kb * 4 + q2;
            int4 v = make_int4(0, 0, 0, 0);
            if (row < N_NODES) {
                const float4* sp = emb + (size_t)entity[row] * 32 + oct * 2;
                v = pack8(sp[0], sp[1]);
            }
            *(int4*)&xrf[c * 8] = v;
        }
        __syncthreads();

        int w_ = t >> 6, l = t & 63, n = l & 15, q = l >> 4;
        f32x4 acc[2][4] = {};
#pragma unroll
        for (int kb = 0; kb < 4; kb++) {
            bf16x8 a[4];
#pragma unroll
            for (int rt = 0; rt < 4; rt++) a[rt] = *(const bf16x8*)&xrf[((rt * 4 + kb) * 64 + l) * 8];
            int kbase = kb * 32 + q * 8;
#pragma unroll
            for (int c = 0; c < 2; c++) {
                int col = (w_ * 2 + c) * 16 + n;
                bf16x8 b;
#pragma unroll
                for (int j = 0; j < 8; j++) b[j] = (__bf16)root1[(kbase + j) * DIM + col];
#pragma unroll
                for (int rt = 0; rt < 4; rt++)
                    acc[c][rt] = __builtin_amdgcn_mfma_f32_16x16x32_bf16(a[rt], b, acc[c][rt], 0, 0, 0);
            }
        }
#pragma unroll
        for (int c = 0; c < 2; c++) {
            int col = (w_ * 2 + c) * 16 + n;
#pragma unroll
            for (int rt = 0; rt < 4; rt++) {
#pragma unroll
                for (int rg = 0; rg < 4; rg++) {
                    int row = n0 + rt * 16 + q * 4 + rg;
                    if (row < N_NODES)
                        racc1[(size_t)row * DIM + col] = acc[c][rt][rg];
                }
            }
        }
    } else {
        // ---- gather + zero ----
        int pb = blockIdx.x - GATHER_BASE;
        int gtid = pb * 256 + t;
        int gsz = (PREP_GRID - GATHER_BASE) * 256;
        int total4 = N_NODES * DIM / 4;
        for (int i = gtid; i < total4; i += gsz) {
            int n = i >> 5, rem = i & 31;
            float4 v = emb[(size_t)entity[n] * 32 + rem];
            ushort4 s;
            s.x = f2b(v.x); s.y = f2b(v.y); s.z = f2b(v.z); s.w = f2b(v.w);
            xb4[i] = s;
        }
        float4 z = make_float4(0.f, 0.f, 0.f, 0.f);
        for (int i = gtid; i < zcount4; i += gsz) zreg[i] = z;
    }
}

// ---------- msg: blocks [0,948): half-relation each — self-plan over half of etype,
//            inline logits, MFMA messages, alpha-weighted atomic scatter to accm + den.
//            blocks [948, 948+nroot): rootgemm on xb with rootT -> racc (msg2 only). ----------
__global__ __launch_bounds__(256) void msg_kernel(const unsigned short* __restrict__ xb,
                                                  const unsigned short* __restrict__ W,
                                                  const float* __restrict__ wlog,
                                                  const int* __restrict__ src,
                                                  const int* __restrict__ dst,
                                                  const int* __restrict__ etype,
                                                  float* __restrict__ den,
                                                  float* __restrict__ accm,
                                                  const unsigned short* __restrict__ rootT,
                                                  float* __restrict__ racc) {
    __shared__ __align__(16) unsigned short wt[128 * 136];   // swizzled W_r / xrf alias
    __shared__ __align__(16) unsigned short xjf[8192];
    __shared__ __align__(16) float wf[DIM];
    __shared__ float scf[TILE_E];
    __shared__ int sdd[TILE_E];
    __shared__ int ssrc[TILE_E];
    __shared__ int elist[LELIST];
    __shared__ int lcnt;

    int t = threadIdx.x;
    if ((int)blockIdx.x < MSG_REL_BLKS) {
        int r = blockIdx.x >> 1, half = blockIdx.x & 1;
        const unsigned short* Wr = W + (size_t)r * (DIM * DIM);
        if (t == 0) lcnt = 0;
#pragma unroll
        for (int p = 0; p < 8; p++) {
            int c = t + 256 * p;
            int k = c >> 4, oct = c & 15;
            int4 v = *(const int4*)(Wr + k * DIM + oct * 8);
            int oct2 = oct ^ (((k >> 3) & 7) << 1);
            *(int4*)&wt[k * 136 + oct2 * 8] = v;
        }
        if (t < 32) ((float4*)wf)[t] = ((const float4*)(wlog + (size_t)r * DIM))[t];
        __syncthreads();

        // plan: scan this block's half of etype
        int lane = t & 63;
        for (int it = half * 16; it < half * 16 + 16; it++) {
            int idx = it * 256 + t;
            int4 ev = ((const int4*)etype)[idx];
#pragma unroll
            for (int j = 0; j < 4; j++) {
                int etj = (j == 0) ? ev.x : (j == 1) ? ev.y : (j == 2) ? ev.z : ev.w;
                bool m = (etj == r);
                unsigned long long bal = __ballot(m);
                int tot = __popcll(bal);
                if (tot) {
                    int base = 0;
                    if (lane == 0) base = atomicAdd(&lcnt, tot);
                    base = __shfl(base, 0, 64);
                    if (m) {
                        int pre = __popcll(bal & ((1ull << lane) - 1ull));
                        int p_ = base + pre;
                        if (p_ < LELIST) elist[p_] = idx * 4 + j;
                    }
                }
            }
        }
        __syncthreads();
        int cnt = min(lcnt, LELIST);
        if (cnt == 0) return;

        int w = t >> 6, l = t & 63, n = l & 15, q = l >> 4;
        int el4 = t >> 2, l4 = t & 3;

        for (int t0 = 0; t0 < cnt; t0 += TILE_E) {
            int nE = min(TILE_E, cnt - t0);
            if (t < TILE_E) {
                if (t < nE) {
                    int e = elist[t0 + t];
                    ssrc[t] = src[e];
                    sdd[t]  = dst[e];
                } else { ssrc[t] = 0; sdd[t] = 0; }
            }
            __syncthreads();

            // logits: 4 lanes per edge
            {
                int s_ = ssrc[el4], d_ = sdd[el4];
                const int4* xj = (const int4*)(xb + (size_t)s_ * DIM) + l4 * 4;
                const int4* xi = (const int4*)(xb + (size_t)d_ * DIM) + l4 * 4;
                const float4* wv = (const float4*)&wf[l4 * 32];
                float v = 0.f;
#pragma unroll
                for (int u = 0; u < 4; u++) {
                    int4 a = xj[u]; int4 bb = xi[u];
                    float4 w0 = wv[u * 2], w1 = wv[u * 2 + 1];
                    v += dot2bf((unsigned)a.x, (unsigned)bb.x, w0.x, w0.y)
                       + dot2bf((unsigned)a.y, (unsigned)bb.y, w0.z, w0.w)
                       + dot2bf((unsigned)a.z, (unsigned)bb.z, w1.x, w1.y)
                       + dot2bf((unsigned)a.w, (unsigned)bb.w, w1.z, w1.w);
                }
                v += __shfl_xor(v, 1, 64);
                v += __shfl_xor(v, 2, 64);
                if (l4 == 0) {
                    if (el4 < nE) {
                        float a = expf(v);
                        scf[el4] = a;
                        atomicAdd(&den[d_], a);
                    } else scf[el4] = 0.f;
                }
            }

            // stage A-frags
#pragma unroll
            for (int p = 0; p < 4; p++) {
                int c = t + 256 * p;
                int g = c >> 6;
                int rt = g >> 2, kb = g & 3;
                int q2 = (c >> 4) & 3, m = c & 15;
                int e = rt * 16 + m;
                int oct = kb * 4 + q2;
                int4 v = make_int4(0, 0, 0, 0);
                if (e < nE) v = *(const int4*)(xb + (size_t)ssrc[e] * DIM + oct * 8);
                *(int4*)&xjf[c * 8] = v;
            }
            __syncthreads();

            f32x4 acc[2][4] = {};
#pragma unroll
            for (int kb = 0; kb < 4; kb++) {
                bf16x8 a[4];
#pragma unroll
                for (int rt = 0; rt < 4; rt++) a[rt] = *(const bf16x8*)&xjf[((rt * 4 + kb) * 64 + l) * 8];
                int kbase = kb * 32 + q * 8;
                int sx = ((kb * 4 + q) & 7) << 4;
#pragma unroll
                for (int c = 0; c < 2; c++) {
                    int ob = ((w * 2 + c) * 16 + n) ^ sx;
                    bf16x8 bb;
#pragma unroll
                    for (int j = 0; j < 8; j++) bb[j] = u2b(wt[(kbase + j) * 136 + ob]);
#pragma unroll
                    for (int rt = 0; rt < 4; rt++)
                        acc[c][rt] = __builtin_amdgcn_mfma_f32_16x16x32_bf16(a[rt], bb, acc[c][rt], 0, 0, 0);
                }
            }
#pragma unroll
            for (int c = 0; c < 2; c++) {
                int col = (w * 2 + c) * 16 + n;
#pragma unroll
                for (int rt = 0; rt < 4; rt++) {
#pragma unroll
                    for (int rg = 0; rg < 4; rg++) {
                        int e = rt * 16 + q * 4 + rg;
                        if (e < nE)
                            atomicAdd(&accm[(size_t)sdd[e] * DIM + col], scf[e] * acc[c][rt][rg]);
                    }
                }
            }
            __syncthreads();
        }
    } else {
        // ---- rootgemm (msg2 only): racc = xb @ rootT  (xb here = hb, already relu'd) ----
        int n0 = ((int)blockIdx.x - MSG_REL_BLKS) * 64;
        unsigned short* xrf = wt;   // alias 16 KB
#pragma unroll
        for (int p = 0; p < 4; p++) {
            int c = t + 256 * p;
            int g = c >> 6;
            int rt = g >> 2, kb = g & 3;
            int q2 = (c >> 4) & 3, m = c & 15;
            int row = n0 + rt * 16 + m;
            int oct = kb * 4 + q2;
            int4 v = make_int4(0, 0, 0, 0);
            if (row < N_NODES) v = *(const int4*)(xb + (size_t)row * DIM + oct * 8);
            *(int4*)&xrf[c * 8] = v;
        }
        __syncthreads();

        int w_ = t >> 6, l = t & 63, n = l & 15, q = l >> 4;
        f32x4 acc[2][4] = {};
#pragma unroll
        for (int kb = 0; kb < 4; kb++) {
            bf16x8 a[4];
#pragma unroll
            for (int rt = 0; rt < 4; rt++) a[rt] = *(const bf16x8*)&xrf[((rt * 4 + kb) * 64 + l) * 8];
            int kbase = kb * 32 + q * 8;
#pragma unroll
            for (int c = 0; c < 2; c++) {
                int col = (w_ * 2 + c) * 16 + n;
                bf16x8 bb = *(const bf16x8*)(rootT + (size_t)col * DIM + kbase);
#pragma unroll
                for (int rt = 0; rt < 4; rt++)
                    acc[c][rt] = __builtin_amdgcn_mfma_f32_16x16x32_bf16(a[rt], bb, acc[c][rt], 0, 0, 0);
            }
        }
#pragma unroll
        for (int c = 0; c < 2; c++) {
            int col = (w_ * 2 + c) * 16 + n;
#pragma unroll
            for (int rt = 0; rt < 4; rt++) {
#pragma unroll
                for (int rg = 0; rg < 4; rg++) {
                    int row = n0 + rt * 16 + q * 4 + rg;
                    if (row < N_NODES)
                        racc[(size_t)row * DIM + col] = acc[c][rt][rg];
                }
            }
        }
    }
}

// ---------- merge: val = racc + bias + accm/den; outb -> relu+bf16, outf -> fp32 ----------
__global__ __launch_bounds__(256) void merge_kernel(const float4* __restrict__ racc,
                                                    const float4* __restrict__ accm,
                                                    const float* __restrict__ den,
                                                    const float* __restrict__ bias,
                                                    float4* __restrict__ outf,
                                                    ushort4* __restrict__ outb) {
    int gtid = blockIdx.x * 256 + threadIdx.x;
    const int tot4 = N_NODES * (DIM / 4);
    for (int i = gtid; i < tot4; i += (int)gridDim.x * 256) {
        int row = i >> 5;
        int c0 = (i & 31) * 4;
        float4 rv = racc[i];
        float4 mv = accm[i];
        float4 bo = *(const float4*)&bias[c0];
        float dv = den[row];
        float inv = dv > 0.f ? 1.0f / dv : 0.f;
        float4 v;
        v.x = rv.x + bo.x + mv.x * inv;
        v.y = rv.y + bo.y + mv.y * inv;
        v.z = rv.z + bo.z + mv.z * inv;
        v.w = rv.w + bo.w + mv.w * inv;
        if (outb) {
            ushort4 s;
            s.x = f2b(fmaxf(v.x, 0.f)); s.y = f2b(fmaxf(v.y, 0.f));
            s.z = f2b(fmaxf(v.z, 0.f)); s.w = f2b(fmaxf(v.w, 0.f));
            outb[i] = s;
        } else {
            outf[i] = v;
        }
    }
}

extern "C" void kernel_launch(void* const* d_in, const int* in_sizes, int n_in,
                              void* d_out, int out_size, void* d_ws, size_t ws_size,
                              hipStream_t stream) {
    const int N = N_NODES, E = N_EDGES, R = N_REL;

    const int* entity = (const int*)d_in[0];
    const int* eidx   = (const int*)d_in[1];
    const int* src    = eidx;
    const int* dst    = eidx + E;
    const int* etype  = (const int*)d_in[2];
    const float* emb  = (const float*)d_in[3];
    const float* basis1 = (const float*)d_in[4];
    const float* att1   = (const float*)d_in[5];
    const float* w1     = (const float*)d_in[6];
    const float* root1  = (const float*)d_in[7];
    const float* bias1  = (const float*)d_in[8];
    const float* basis2 = (const float*)d_in[9];
    const float* att2   = (const float*)d_in[10];
    const float* w2     = (const float*)d_in[11];
    const float* root2  = (const float*)d_in[12];
    const float* bias2  = (const float*)d_in[13];
    float* out = (float*)d_out;

    size_t off = 0;
    auto alloc = [&](size_t bytes) -> void* {
        void* p = (char*)d_ws + off;
        off += (bytes + 255) & ~(size_t)255;
        return p;
    };
    unsigned short* W1 = (unsigned short*)alloc((size_t)R * DIM * DIM * 2);
    unsigned short* W2 = (unsigned short*)alloc((size_t)R * DIM * DIM * 2);
    unsigned short* xb = (unsigned short*)alloc((size_t)N * DIM * 2);
    unsigned short* hb = (unsigned short*)alloc((size_t)N * DIM * 2);
    float* racc1  = (float*)alloc((size_t)N * DIM * 4);
    float* racc2  = (float*)alloc((size_t)N * DIM * 4);
    // zero region: den1 | den2 | accm1 | accm2 (contiguous)
    float* zreg   = (float*)alloc(((size_t)2 * N + (size_t)2 * N * DIM) * 4);
    float* den1   = zreg;
    float* den2   = zreg + N;
    float* accm1  = zreg + 2 * N;
    float* accm2  = zreg + 2 * N + (size_t)N * DIM;
    unsigned short* rootT2 = (unsigned short*)alloc((size_t)DIM * DIM * 2);

    int zcount4 = (2 * N + 2 * N * DIM) / 4;

    // ---- prep: wmix + rootT2 + rootgemm1 + gather/zero ----
    prep_kernel<<<PREP_GRID, 256, 0, stream>>>(
        (const float4*)emb, entity, (ushort4*)xb, (float4*)zreg, zcount4,
        att1, basis1, W1, att2, basis2, W2, root1, racc1, root2, rootT2);

    // ---- layer 1 ----
    msg_kernel<<<MSG_REL_BLKS, 256, 0, stream>>>(xb, W1, w1, src, dst, etype,
                                                 den1, accm1, nullptr, nullptr);
    merge_kernel<<<MERGE_GRID, 256, 0, stream>>>((const float4*)racc1, (const float4*)accm1,
                                                 den1, bias1, nullptr, (ushort4*)hb);

    // ---- layer 2: msg + rootgemm2 in one dispatch (both only READ hb) ----
    msg_kernel<<<MSG_REL_BLKS + RG1_BLKS, 256, 0, stream>>>(hb, W2, w2, src, dst, etype,
                                                            den2, accm2, rootT2, racc2);
    merge_kernel<<<MERGE_GRID, 256, 0, stream>>>((const float4*)racc2, (const float4*)accm2,
                                                 den2, bias2, (float4*)out, nullptr);
}

// Round 6
// 209.180 us; speedup vs baseline: 1.0896x; 1.0295x over previous
//
#include <hip/hip_runtime.h>
#include <hip/hip_bf16.h>

#define N_NODES 20000
#define N_EDGES 32768
#define DIM 128
#define N_REL 474
#define N_BASIS 64
#define TILE_E 64
#define WSTRIDE 264                         // LDS row stride (shorts), 264*64*2 = 33792 B
#define LELIST 1024

// prep block layout
#define WMIX_BLKS 1024                      // (2 layers) x (64 col-blocks) x (8 rel-groups)
#define ROOTT_BLKS 2                        // rootT1/rootT2 transpose-pack
#define GATHER_BASE (WMIX_BLKS + ROOTT_BLKS)  // 1026
#define PREP_GRID 1664                      // 638 gather/zero blocks

#define MSG_REL_BLKS (2 * N_REL)            // 948: two blocks per relation
#define RG_BLKS ((N_NODES + 63) / 64)       // 313: rootgemm rides inside msg dispatch
#define MSG_GRID (MSG_REL_BLKS + RG_BLKS)   // 1261
#define MERGE_GRID 1024

typedef __bf16 bf16x8 __attribute__((ext_vector_type(8)));
typedef float f32x4 __attribute__((ext_vector_type(4)));

// ---------- helpers ----------
__device__ __forceinline__ unsigned short f2b(float f) {   // RNE fp32 -> bf16 bits
    unsigned u = __float_as_uint(f);
    unsigned r = (u + 0x7FFFu + ((u >> 16) & 1u)) >> 16;
    return (unsigned short)r;
}
__device__ __forceinline__ float b2f(unsigned short s) {
    return __uint_as_float(((unsigned)s) << 16);
}
__device__ __forceinline__ __bf16 u2b(unsigned short u) {
    union { unsigned short u; __bf16 b; } c; c.u = u; return c.b;
}
__device__ __forceinline__ float dot2bf(unsigned a, unsigned b, float wx, float wy) {
    return b2f((unsigned short)(a & 0xFFFFu)) * wx * b2f((unsigned short)(b & 0xFFFFu))
         + b2f((unsigned short)(a >> 16)) * wy * b2f((unsigned short)(b >> 16));
}

// ---------- prep: [0,1024) wmix (one rel-group each); [1024,1026) rootT pack;
//            [1026,1664) gather emb->bf16 + zero den/accm ----------
__global__ __launch_bounds__(256) void prep_kernel(const float4* __restrict__ emb,
                                                   const int* __restrict__ entity,
                                                   ushort4* __restrict__ xb4,
                                                   float4* __restrict__ zreg, int zcount4,
                                                   const float* __restrict__ att1,
                                                   const float* __restrict__ basis1,
                                                   unsigned short* __restrict__ W1,
                                                   const float* __restrict__ att2,
                                                   const float* __restrict__ basis2,
                                                   unsigned short* __restrict__ W2,
                                                   const float* __restrict__ root1,
                                                   unsigned short* __restrict__ rootT1,
                                                   const float* __restrict__ root2,
                                                   unsigned short* __restrict__ rootT2) {
    __shared__ __align__(16) unsigned short bt[64 * WSTRIDE];   // 33792 B
    int t = threadIdx.x;
    if (blockIdx.x < WMIX_BLKS) {
        // ---- wmix: W[r0:r0+64, io0:io0+256] = att . basis for ONE rel-group ----
        int wi = blockIdx.x;
        int layer = wi >> 9;                       // 0: layer1, 1: layer2
        int cb = (wi >> 3) & 63;                   // col-block
        int rg = wi & 7;                           // rel-group
        const float* att   = layer ? att2 : att1;
        const float* basis = layer ? basis2 : basis1;
        unsigned short* W  = layer ? W2 : W1;
        int io0 = cb * 256;
        int r0 = rg * 64;
        // stage basis tile [64 k][256 cols] bf16, XOR-swizzled (L2/L3-hot re-read)
#pragma unroll
        for (int p = 0; p < 16; p++) {
            int c = t + 256 * p;
            int k = c >> 6, of = c & 63;
            float4 v = *(const float4*)(basis + (size_t)k * (DIM * DIM) + io0 + of * 4);
            ushort4 s;
            s.x = f2b(v.x); s.y = f2b(v.y); s.z = f2b(v.z); s.w = f2b(v.w);
            int ofx = of ^ (((k >> 3) & 7) << 2);
            *(ushort4*)&bt[k * WSTRIDE + ofx * 4] = s;
        }
        __syncthreads();

        int w = t >> 6, l = t & 63, n = l & 15, q = l >> 4;
        // b-frags from LDS (swizzled)
        bf16x8 bfr[2][4];
#pragma unroll
        for (int kb = 0; kb < 2; kb++) {
            int kbase = kb * 32 + q * 8;
            int sx = ((kb * 4 + q) & 7) << 4;
#pragma unroll
            for (int c = 0; c < 4; c++) {
                int ob = (w * 64 + c * 16 + n) ^ sx;
#pragma unroll
                for (int j = 0; j < 8; j++) bfr[kb][c][j] = u2b(bt[(kbase + j) * WSTRIDE + ob]);
            }
        }
        __syncthreads();   // bt free for store staging

        f32x4 acc[4][4] = {};                      // [rt][c]
#pragma unroll
        for (int kb = 0; kb < 2; kb++) {
            int kbase = kb * 32 + q * 8;
            bf16x8 a[4];
#pragma unroll
            for (int rt = 0; rt < 4; rt++) {
                int rm = min(r0 + rt * 16 + n, N_REL - 1);
                const float4* ap = (const float4*)(att + (size_t)rm * N_BASIS + kbase);
                float4 u0 = ap[0], u1 = ap[1];
                a[rt][0] = (__bf16)u0.x; a[rt][1] = (__bf16)u0.y;
                a[rt][2] = (__bf16)u0.z; a[rt][3] = (__bf16)u0.w;
                a[rt][4] = (__bf16)u1.x; a[rt][5] = (__bf16)u1.y;
                a[rt][6] = (__bf16)u1.z; a[rt][7] = (__bf16)u1.w;
            }
#pragma unroll
            for (int c = 0; c < 4; c++) {
#pragma unroll
                for (int rt = 0; rt < 4; rt++)
                    acc[rt][c] = __builtin_amdgcn_mfma_f32_16x16x32_bf16(a[rt], bfr[kb][c], acc[rt][c], 0, 0, 0);
            }
        }
        // stage 64 r-rows x 256 cols into bt, then coalesced 512B-per-row stores
#pragma unroll
        for (int rt = 0; rt < 4; rt++) {
#pragma unroll
            for (int c = 0; c < 4; c++) {
#pragma unroll
                for (int g = 0; g < 4; g++)
                    bt[(rt * 16 + q * 4 + g) * WSTRIDE + w * 64 + c * 16 + n] = f2b(acc[rt][c][g]);
            }
        }
        __syncthreads();
        int srow = t >> 2, sseg = t & 3;
        int rr = r0 + srow;
        if (rr < N_REL) {
            const int4* sp = (const int4*)&bt[srow * WSTRIDE];
            unsigned short* wp = W + (size_t)rr * (DIM * DIM) + io0;
#pragma unroll
            for (int ii = 0; ii < 8; ii++) {
                int i = (ii + sseg * 2) & 7;          // seg-rotated LDS reads: ~conflict-free
                int4 v = sp[sseg * 8 + i];
                *(int4*)(wp + sseg * 64 + i * 8) = v;
            }
        }
    } else if (blockIdx.x < GATHER_BASE) {
        // ---- rootT pack: rootT[o][k] = bf16(root[k][o]) ----
        int wi2 = blockIdx.x - WMIX_BLKS;           // 0: root1, 1: root2
        const float* rm = wi2 ? root2 : root1;
        unsigned short* rt_ = wi2 ? rootT2 : rootT1;
        unsigned short* sb16 = bt;                  // [k:128][stride 132]
#pragma unroll
        for (int p = 0; p < 16; p++) {
            int idx = t + 256 * p;
            int k = idx >> 5, o4 = idx & 31;
            float4 v = ((const float4*)rm)[idx];
            ushort4 s;
            s.x = f2b(v.x); s.y = f2b(v.y); s.z = f2b(v.z); s.w = f2b(v.w);
            *(ushort4*)&sb16[k * 132 + o4 * 4] = s;
        }
        __syncthreads();
        int o = t >> 1, kh = (t & 1) * 64;
#pragma unroll
        for (int i = 0; i < 16; i++) {
            int k0 = kh + i * 4;
            ushort4 s;
            s.x = sb16[(k0 + 0) * 132 + o];
            s.y = sb16[(k0 + 1) * 132 + o];
            s.z = sb16[(k0 + 2) * 132 + o];
            s.w = sb16[(k0 + 3) * 132 + o];
            *(ushort4*)&rt_[o * DIM + k0] = s;
        }
    } else {
        // ---- gather + zero ----
        int pb = blockIdx.x - GATHER_BASE;
        int gtid = pb * 256 + t;
        int gsz = (PREP_GRID - GATHER_BASE) * 256;
        int total4 = N_NODES * DIM / 4;
        for (int i = gtid; i < total4; i += gsz) {
            int n = i >> 5, rem = i & 31;
            float4 v = emb[(size_t)entity[n] * 32 + rem];
            ushort4 s;
            s.x = f2b(v.x); s.y = f2b(v.y); s.z = f2b(v.z); s.w = f2b(v.w);
            xb4[i] = s;
        }
        float4 z = make_float4(0.f, 0.f, 0.f, 0.f);
        for (int i = gtid; i < zcount4; i += gsz) zreg[i] = z;
    }
}

// ---------- msg: blocks [0,948): half-relation each — self-plan over half of etype,
//            inline logits, MFMA messages, alpha-weighted atomic scatter to accm + den.
//            blocks [948,1261): rootgemm racc = xb @ rootT (one 16B B-load per frag). ----------
__global__ __launch_bounds__(256) void msg_kernel(const unsigned short* __restrict__ xb,
                                                  const unsigned short* __restrict__ W,
                                                  const float* __restrict__ wlog,
                                                  const int* __restrict__ src,
                                                  const int* __restrict__ dst,
                                                  const int* __restrict__ etype,
                                                  float* __restrict__ den,
                                                  float* __restrict__ accm,
                                                  const unsigned short* __restrict__ rootT,
                                                  float* __restrict__ racc) {
    __shared__ __align__(16) unsigned short wt[128 * 136];   // swizzled W_r / xrf alias
    __shared__ __align__(16) unsigned short xjf[8192];
    __shared__ __align__(16) float wf[DIM];
    __shared__ float scf[TILE_E];
    __shared__ int sdd[TILE_E];
    __shared__ int ssrc[TILE_E];
    __shared__ int elist[LELIST];
    __shared__ int lcnt;

    int t = threadIdx.x;
    if ((int)blockIdx.x < MSG_REL_BLKS) {
        int r = blockIdx.x >> 1, half = blockIdx.x & 1;
        const unsigned short* Wr = W + (size_t)r * (DIM * DIM);
        if (t == 0) lcnt = 0;
#pragma unroll
        for (int p = 0; p < 8; p++) {
            int c = t + 256 * p;
            int k = c >> 4, oct = c & 15;
            int4 v = *(const int4*)(Wr + k * DIM + oct * 8);
            int oct2 = oct ^ (((k >> 3) & 7) << 1);
            *(int4*)&wt[k * 136 + oct2 * 8] = v;
        }
        if (t < 32) ((float4*)wf)[t] = ((const float4*)(wlog + (size_t)r * DIM))[t];
        __syncthreads();

        // plan: scan this block's half of etype
        int lane = t & 63;
        for (int it = half * 16; it < half * 16 + 16; it++) {
            int idx = it * 256 + t;
            int4 ev = ((const int4*)etype)[idx];
#pragma unroll
            for (int j = 0; j < 4; j++) {
                int etj = (j == 0) ? ev.x : (j == 1) ? ev.y : (j == 2) ? ev.z : ev.w;
                bool m = (etj == r);
                unsigned long long bal = __ballot(m);
                int tot = __popcll(bal);
                if (tot) {
                    int base = 0;
                    if (lane == 0) base = atomicAdd(&lcnt, tot);
                    base = __shfl(base, 0, 64);
                    if (m) {
                        int pre = __popcll(bal & ((1ull << lane) - 1ull));
                        int p_ = base + pre;
                        if (p_ < LELIST) elist[p_] = idx * 4 + j;
                    }
                }
            }
        }
        __syncthreads();
        int cnt = min(lcnt, LELIST);
        if (cnt == 0) return;

        int w = t >> 6, l = t & 63, n = l & 15, q = l >> 4;
        int el4 = t >> 2, l4 = t & 3;

        for (int t0 = 0; t0 < cnt; t0 += TILE_E) {
            int nE = min(TILE_E, cnt - t0);
            if (t < TILE_E) {
                if (t < nE) {
                    int e = elist[t0 + t];
                    ssrc[t] = src[e];
                    sdd[t]  = dst[e];
                } else { ssrc[t] = 0; sdd[t] = 0; }
            }
            __syncthreads();

            // logits: 4 lanes per edge
            {
                int s_ = ssrc[el4], d_ = sdd[el4];
                const int4* xj = (const int4*)(xb + (size_t)s_ * DIM) + l4 * 4;
                const int4* xi = (const int4*)(xb + (size_t)d_ * DIM) + l4 * 4;
                const float4* wv = (const float4*)&wf[l4 * 32];
                float v = 0.f;
#pragma unroll
                for (int u = 0; u < 4; u++) {
                    int4 a = xj[u]; int4 bb = xi[u];
                    float4 w0 = wv[u * 2], w1 = wv[u * 2 + 1];
                    v += dot2bf((unsigned)a.x, (unsigned)bb.x, w0.x, w0.y)
                       + dot2bf((unsigned)a.y, (unsigned)bb.y, w0.z, w0.w)
                       + dot2bf((unsigned)a.z, (unsigned)bb.z, w1.x, w1.y)
                       + dot2bf((unsigned)a.w, (unsigned)bb.w, w1.z, w1.w);
                }
                v += __shfl_xor(v, 1, 64);
                v += __shfl_xor(v, 2, 64);
                if (l4 == 0) {
                    if (el4 < nE) {
                        float a = expf(v);
                        scf[el4] = a;
                        atomicAdd(&den[d_], a);
                    } else scf[el4] = 0.f;
                }
            }

            // stage A-frags
#pragma unroll
            for (int p = 0; p < 4; p++) {
                int c = t + 256 * p;
                int g = c >> 6;
                int rt = g >> 2, kb = g & 3;
                int q2 = (c >> 4) & 3, m = c & 15;
                int e = rt * 16 + m;
                int oct = kb * 4 + q2;
                int4 v = make_int4(0, 0, 0, 0);
                if (e < nE) v = *(const int4*)(xb + (size_t)ssrc[e] * DIM + oct * 8);
                *(int4*)&xjf[c * 8] = v;
            }
            __syncthreads();

            f32x4 acc[2][4] = {};
#pragma unroll
            for (int kb = 0; kb < 4; kb++) {
                bf16x8 a[4];
#pragma unroll
                for (int rt = 0; rt < 4; rt++) a[rt] = *(const bf16x8*)&xjf[((rt * 4 + kb) * 64 + l) * 8];
                int kbase = kb * 32 + q * 8;
                int sx = ((kb * 4 + q) & 7) << 4;
#pragma unroll
                for (int c = 0; c < 2; c++) {
                    int ob = ((w * 2 + c) * 16 + n) ^ sx;
                    bf16x8 bb;
#pragma unroll
                    for (int j = 0; j < 8; j++) bb[j] = u2b(wt[(kbase + j) * 136 + ob]);
#pragma unroll
                    for (int rt = 0; rt < 4; rt++)
                        acc[c][rt] = __builtin_amdgcn_mfma_f32_16x16x32_bf16(a[rt], bb, acc[c][rt], 0, 0, 0);
                }
            }
#pragma unroll
            for (int c = 0; c < 2; c++) {
                int col = (w * 2 + c) * 16 + n;
#pragma unroll
                for (int rt = 0; rt < 4; rt++) {
#pragma unroll
                    for (int rg = 0; rg < 4; rg++) {
                        int e = rt * 16 + q * 4 + rg;
                        if (e < nE)
                            atomicAdd(&accm[(size_t)sdd[e] * DIM + col], scf[e] * acc[c][rt][rg]);
                    }
                }
            }
            __syncthreads();
        }
    } else {
        // ---- rootgemm: racc = xb @ rootT ----
        int n0 = ((int)blockIdx.x - MSG_REL_BLKS) * 64;
        unsigned short* xrf = wt;   // alias 16 KB
#pragma unroll
        for (int p = 0; p < 4; p++) {
            int c = t + 256 * p;
            int g = c >> 6;
            int rt = g >> 2, kb = g & 3;
            int q2 = (c >> 4) & 3, m = c & 15;
            int row = n0 + rt * 16 + m;
            int oct = kb * 4 + q2;
            int4 v = make_int4(0, 0, 0, 0);
            if (row < N_NODES) v = *(const int4*)(xb + (size_t)row * DIM + oct * 8);
            *(int4*)&xrf[c * 8] = v;
        }
        __syncthreads();

        int w_ = t >> 6, l = t & 63, n = l & 15, q = l >> 4;
        f32x4 acc[2][4] = {};
#pragma unroll
        for (int kb = 0; kb < 4; kb++) {
            bf16x8 a[4];
#pragma unroll
            for (int rt = 0; rt < 4; rt++) a[rt] = *(const bf16x8*)&xrf[((rt * 4 + kb) * 64 + l) * 8];
            int kbase = kb * 32 + q * 8;
#pragma unroll
            for (int c = 0; c < 2; c++) {
                int col = (w_ * 2 + c) * 16 + n;
                bf16x8 bb = *(const bf16x8*)(rootT + (size_t)col * DIM + kbase);
#pragma unroll
                for (int rt = 0; rt < 4; rt++)
                    acc[c][rt] = __builtin_amdgcn_mfma_f32_16x16x32_bf16(a[rt], bb, acc[c][rt], 0, 0, 0);
            }
        }
#pragma unroll
        for (int c = 0; c < 2; c++) {
            int col = (w_ * 2 + c) * 16 + n;
#pragma unroll
            for (int rt = 0; rt < 4; rt++) {
#pragma unroll
                for (int rg = 0; rg < 4; rg++) {
                    int row = n0 + rt * 16 + q * 4 + rg;
                    if (row < N_NODES)
                        racc[(size_t)row * DIM + col] = acc[c][rt][rg];
                }
            }
        }
    }
}

// ---------- merge: val = racc + bias + accm/den; outb -> relu+bf16, outf -> fp32 ----------
__global__ __launch_bounds__(256) void merge_kernel(const float4* __restrict__ racc,
                                                    const float4* __restrict__ accm,
                                                    const float* __restrict__ den,
                                                    const float* __restrict__ bias,
                                                    float4* __restrict__ outf,
                                                    ushort4* __restrict__ outb) {
    int gtid = blockIdx.x * 256 + threadIdx.x;
    const int tot4 = N_NODES * (DIM / 4);
    for (int i = gtid; i < tot4; i += (int)gridDim.x * 256) {
        int row = i >> 5;
        int c0 = (i & 31) * 4;
        float4 rv = racc[i];
        float4 mv = accm[i];
        float4 bo = *(const float4*)&bias[c0];
        float dv = den[row];
        float inv = dv > 0.f ? 1.0f / dv : 0.f;
        float4 v;
        v.x = rv.x + bo.x + mv.x * inv;
        v.y = rv.y + bo.y + mv.y * inv;
        v.z = rv.z + bo.z + mv.z * inv;
        v.w = rv.w + bo.w + mv.w * inv;
        if (outb) {
            ushort4 s;
            s.x = f2b(fmaxf(v.x, 0.f)); s.y = f2b(fmaxf(v.y, 0.f));
            s.z = f2b(fmaxf(v.z, 0.f)); s.w = f2b(fmaxf(v.w, 0.f));
            outb[i] = s;
        } else {
            outf[i] = v;
        }
    }
}

extern "C" void kernel_launch(void* const* d_in, const int* in_sizes, int n_in,
                              void* d_out, int out_size, void* d_ws, size_t ws_size,
                              hipStream_t stream) {
    const int N = N_NODES, E = N_EDGES, R = N_REL;

    const int* entity = (const int*)d_in[0];
    const int* eidx   = (const int*)d_in[1];
    const int* src    = eidx;
    const int* dst    = eidx + E;
    const int* etype  = (const int*)d_in[2];
    const float* emb  = (const float*)d_in[3];
    const float* basis1 = (const float*)d_in[4];
    const float* att1   = (const float*)d_in[5];
    const float* w1     = (const float*)d_in[6];
    const float* root1  = (const float*)d_in[7];
    const float* bias1  = (const float*)d_in[8];
    const float* basis2 = (const float*)d_in[9];
    const float* att2   = (const float*)d_in[10];
    const float* w2     = (const float*)d_in[11];
    const float* root2  = (const float*)d_in[12];
    const float* bias2  = (const float*)d_in[13];
    float* out = (float*)d_out;

    size_t off = 0;
    auto alloc = [&](size_t bytes) -> void* {
        void* p = (char*)d_ws + off;
        off += (bytes + 255) & ~(size_t)255;
        return p;
    };
    unsigned short* W1 = (unsigned short*)alloc((size_t)R * DIM * DIM * 2);
    unsigned short* W2 = (unsigned short*)alloc((size_t)R * DIM * DIM * 2);
    unsigned short* xb = (unsigned short*)alloc((size_t)N * DIM * 2);
    unsigned short* hb = (unsigned short*)alloc((size_t)N * DIM * 2);
    float* racc1  = (float*)alloc((size_t)N * DIM * 4);
    float* racc2  = (float*)alloc((size_t)N * DIM * 4);
    // zero region: den1 | den2 | accm1 | accm2 (contiguous)
    float* zreg   = (float*)alloc(((size_t)2 * N + (size_t)2 * N * DIM) * 4);
    float* den1   = zreg;
    float* den2   = zreg + N;
    float* accm1  = zreg + 2 * N;
    float* accm2  = zreg + 2 * N + (size_t)N * DIM;
    unsigned short* rootT1 = (unsigned short*)alloc((size_t)DIM * DIM * 2);
    unsigned short* rootT2 = (unsigned short*)alloc((size_t)DIM * DIM * 2);

    int zcount4 = (2 * N + 2 * N * DIM) / 4;

    // ---- prep: wmix (1024-way) + rootT1/rootT2 + gather/zero ----
    prep_kernel<<<PREP_GRID, 256, 0, stream>>>(
        (const float4*)emb, entity, (ushort4*)xb, (float4*)zreg, zcount4,
        att1, basis1, W1, att2, basis2, W2, root1, rootT1, root2, rootT2);

    // ---- layer 1: msg + rootgemm1 in one dispatch ----
    msg_kernel<<<MSG_GRID, 256, 0, stream>>>(xb, W1, w1, src, dst, etype,
                                             den1, accm1, rootT1, racc1);
    merge_kernel<<<MERGE_GRID, 256, 0, stream>>>((const float4*)racc1, (const float4*)accm1,
                                                 den1, bias1, nullptr, (ushort4*)hb);

    // ---- layer 2: msg + rootgemm2 in one dispatch ----
    msg_kernel<<<MSG_GRID, 256, 0, stream>>>(hb, W2, w2, src, dst, etype,
                                             den2, accm2, rootT2, racc2);
    merge_kernel<<<MERGE_GRID, 256, 0, stream>>>((const float4*)racc2, (const float4*)accm2,
                                                 den2, bias2, (float4*)out, nullptr);
}